// Round 1
// baseline (3730.971 us; speedup 1.0000x reference)
//
#include <hip/hip_runtime.h>
#include <math.h>

#define BB 16
#define LL 48
#define HH 1024
#define NG4 4096      // 4*H
#define NG6 6144      // 6*H
#define K3H 3072      // 3*H
#define RANKH 128
#define MAXN 47       // max nodes per batch (len-1 <= 47)
#define TOTN (BB*MAXN)
#define MAXLVL 48
#define MAXNPL 384    // max nodes in one level (16 batches * 24)

__device__ __forceinline__ float sigf(float x){ return 1.f/(1.f + expf(-x)); }

// ---------------------------------------------------------------------------
// Generic 32x32 LDS-tiled transpose: out[C][R] = in[R][C]^T
__global__ __launch_bounds__(256) void k_transpose(const float* __restrict__ in,
                                                   float* __restrict__ out, int R, int C){
  __shared__ float t[32][33];
  int bx = blockIdx.x*32, by = blockIdx.y*32;
  int x = threadIdx.x, y = threadIdx.y;   // block (32,8)
  #pragma unroll
  for (int i = 0; i < 32; i += 8){
    int r = by + y + i, c = bx + x;
    if (r < R && c < C) t[y+i][x] = in[(size_t)r*C + c];
  }
  __syncthreads();
  #pragma unroll
  for (int i = 0; i < 32; i += 8){
    int r = bx + y + i, c = by + x;       // out dims [C][R]
    if (r < C && c < R) out[(size_t)r*R + c] = t[x][y+i];
  }
}

// ---------------------------------------------------------------------------
// Gx[m][n] = sum_k se[m][k]*Wih[n][k] + bih[n] + bhh[n]
// M=768, N=4096, K=1024.  64x64 tile, K-chunk 16.
__global__ __launch_bounds__(256) void k_gemm_gx(const float* __restrict__ A,
    const float* __restrict__ Bw, const float* __restrict__ bih,
    const float* __restrict__ bhh, float* __restrict__ Cout, int M, int N, int K){
  __shared__ float as[16][68];
  __shared__ float bs[16][68];
  int m0 = blockIdx.x*64, n0 = blockIdx.y*64;
  int tid = threadIdx.x;
  int mt = tid & 15, nt = tid >> 4;
  float acc[4][4] = {};
  for (int k0 = 0; k0 < K; k0 += 16){
    #pragma unroll
    for (int it = 0; it < 4; ++it){
      int idx = it*256 + tid;
      int kk = idx & 15, mm = idx >> 4;
      as[kk][mm] = A[(size_t)(m0+mm)*K + k0 + kk];
      bs[kk][mm] = Bw[(size_t)(n0+mm)*K + k0 + kk];
    }
    __syncthreads();
    #pragma unroll
    for (int kk = 0; kk < 16; ++kk){
      float a4[4], b4[4];
      #pragma unroll
      for (int i = 0; i < 4; ++i) a4[i] = as[kk][mt*4+i];
      #pragma unroll
      for (int i = 0; i < 4; ++i) b4[i] = bs[kk][nt*4+i];
      #pragma unroll
      for (int i = 0; i < 4; ++i)
        #pragma unroll
        for (int j2 = 0; j2 < 4; ++j2) acc[i][j2] += a4[i]*b4[j2];
    }
    __syncthreads();
  }
  #pragma unroll
  for (int i = 0; i < 4; ++i){
    int m = m0 + mt*4 + i;
    #pragma unroll
    for (int j2 = 0; j2 < 4; ++j2){
      int n = n0 + nt*4 + j2;
      Cout[(size_t)m*N + n] = acc[i][j2] + bih[n] + bhh[n];
    }
  }
}

// ---------------------------------------------------------------------------
// One LSTM time step. grid=128 (8 b-pairs x 16 j-chunks), block=256.
// Waves 0,1 -> b0 (k halves), waves 2,3 -> b1. Wt is Whh transposed [1024][4096].
__global__ __launch_bounds__(256) void k_lstm_step(const float* __restrict__ Wt,
    const float* __restrict__ Gx, float* __restrict__ hs, float* __restrict__ cs, int t){
  __shared__ float hsm[2][HH];
  __shared__ float red[2][2][4][64];
  int tid = threadIdx.x;
  int bp = blockIdx.x >> 4, jc = blockIdx.x & 15;
  int w = tid >> 6, l = tid & 63;
  int bl = w >> 1;    // local b 0/1
  int kh = w & 1;     // k-half
  int b0 = bp*2;
  if (t == 0){
    for (int i = tid; i < 2*HH; i += 256) ((float*)hsm)[i] = 0.f;
  } else {
    for (int i = tid; i < 2*HH; i += 256){
      int bb = i >> 10, k = i & 1023;
      ((float*)hsm)[i] = hs[(size_t)((b0+bb)*LL + (t-1))*HH + k];
    }
  }
  __syncthreads();
  int j = jc*64 + l;
  float acc0=0.f, acc1=0.f, acc2=0.f, acc3=0.f;
  const float* hrow = hsm[bl];
  for (int k = kh*512; k < kh*512 + 512; ++k){
    float hk = hrow[k];
    const float* wr = &Wt[(size_t)k*NG4 + j];
    acc0 += wr[0]    * hk;
    acc1 += wr[1024] * hk;
    acc2 += wr[2048] * hk;
    acc3 += wr[3072] * hk;
  }
  red[bl][kh][0][l] = acc0; red[bl][kh][1][l] = acc1;
  red[bl][kh][2][l] = acc2; red[bl][kh][3][l] = acc3;
  __syncthreads();
  if (tid < 128){
    int bb = tid >> 6, jl = tid & 63;
    int b = b0 + bb;
    int jj = jc*64 + jl;
    size_t grow = (size_t)(b*LL + t)*NG4;
    float gi = Gx[grow + 0*HH + jj] + red[bb][0][0][jl] + red[bb][1][0][jl];
    float gf = Gx[grow + 1*HH + jj] + red[bb][0][1][jl] + red[bb][1][1][jl];
    float gu = Gx[grow + 2*HH + jj] + red[bb][0][2][jl] + red[bb][1][2][jl];
    float go = Gx[grow + 3*HH + jj] + red[bb][0][3][jl] + red[bb][1][3][jl];
    float cp = (t == 0) ? 0.f : cs[(size_t)(b*LL + (t-1))*HH + jj];
    float c = sigf(gf)*cp + sigf(gi)*tanhf(gu);
    float h = sigf(go)*tanhf(c);
    cs[(size_t)(b*LL + t)*HH + jj] = c;
    hs[(size_t)(b*LL + t)*HH + jj] = h;
  }
}

// ---------------------------------------------------------------------------
// Per-position rank-MLP score + gumbel noise. grid = B*L blocks, 128 threads.
__global__ __launch_bounds__(128) void k_score(const float* __restrict__ R1t,
    const float* __restrict__ R2, const float* __restrict__ hs,
    const float* __restrict__ gumbel_u, float* __restrict__ score,
    float* __restrict__ snoisy){
  __shared__ float hsm[HH];
  __shared__ float red[128];
  int bt = blockIdx.x;
  int tid = threadIdx.x;
  for (int i = tid; i < HH; i += 128) hsm[i] = hs[(size_t)bt*HH + i];
  __syncthreads();
  float acc = 0.f;
  for (int k = 0; k < HH; ++k) acc += R1t[(size_t)k*RANKH + tid] * hsm[k];
  red[tid] = fmaxf(acc, 0.f) * R2[tid];
  __syncthreads();
  for (int s = 64; s > 0; s >>= 1){
    if (tid < s) red[tid] += red[tid+s];
    __syncthreads();
  }
  if (tid == 0){
    float s = red[0];
    float u = gumbel_u[bt];
    float noise = -logf(-logf(u));
    score[bt]  = s;
    snoisy[bt] = s + noise;
  }
}

// ---------------------------------------------------------------------------
// Build the tree structure for all batches. 1 block, 64 threads (16 active).
// Child encoding: -1 empty, >=10000 leaf t (enc-10000), else global node id.
__global__ __launch_bounds__(64) void k_build(const float* __restrict__ score,
    const float* __restrict__ snoisy, const int* __restrict__ length,
    int* __restrict__ node_l, int* __restrict__ node_r, int* __restrict__ node_x,
    int* __restrict__ node_lvl, int* __restrict__ node_b, int* __restrict__ node_root,
    int* __restrict__ level_count, int* __restrict__ level_off, int* __restrict__ order){
  __shared__ float sc[BB*LL], sn[BB*LL];
  __shared__ int lcount[MAXLVL+1], lcur[MAXLVL+1], loff[MAXLVL+1];
  __shared__ int percnt[BB];
  int tid = threadIdx.x;
  for (int i = tid; i < BB*LL; i += 64){ sc[i] = score[i]; sn[i] = snoisy[i]; }
  for (int i = tid; i <= MAXLVL; i += 64){ lcount[i] = 0; lcur[i] = 0; }
  __syncthreads();
  if (tid < BB){
    int b = tid;
    int len = length[b];
    if (len > LL) len = LL;
    int qs[MAXN], qe[MAXN], qn[MAXN];
    int qh = 0, qt = 0, cnt = 0;
    // root span (len >= 2 guaranteed by the problem: length in [8,48])
    int rootn = cnt++;
    qs[qt] = 0; qe[qt] = len; qn[qt] = rootn; qt++;
    while (qh < qt){
      int s0 = qs[qh], e0 = qe[qh], nid = qn[qh]; qh++;
      float best = sc[b*LL + s0]; int pos = s0;
      for (int t2 = s0+1; t2 < e0; ++t2){
        float v = sc[b*LL + t2];
        if (v > best){ best = v; pos = t2; }
      }
      float bestn = sn[b*LL + s0]; int js = s0;
      for (int t2 = s0+1; t2 < e0; ++t2){
        float v = sn[b*LL + t2];
        if (v > bestn){ bestn = v; js = t2; }
      }
      int gid = b*MAXN + nid;
      node_x[gid] = js;
      node_b[gid] = b;
      node_root[gid] = (nid == 0) ? 1 : 0;
      int ln = pos - s0, enc_l, enc_r;
      if (ln <= 0) enc_l = -1;
      else if (ln == 1) enc_l = 10000 + s0;
      else { int c2 = cnt++; enc_l = b*MAXN + c2; qs[qt]=s0; qe[qt]=pos; qn[qt]=c2; qt++; }
      int rn = e0 - (pos+1);
      if (rn <= 0) enc_r = -1;
      else if (rn == 1) enc_r = 10000 + (pos+1);
      else { int c2 = cnt++; enc_r = b*MAXN + c2; qs[qt]=pos+1; qe[qt]=e0; qn[qt]=c2; qt++; }
      node_l[gid] = enc_l; node_r[gid] = enc_r;
    }
    // levels bottom-up (children always allocated after parents -> reverse order)
    for (int i = cnt-1; i >= 0; --i){
      int gid = b*MAXN + i;
      int el = node_l[gid], er = node_r[gid];
      int llv = (el >= 0 && el < 10000) ? node_lvl[el] : 0;
      int rlv = (er >= 0 && er < 10000) ? node_lvl[er] : 0;
      node_lvl[gid] = 1 + (llv > rlv ? llv : rlv);
    }
    for (int i = 0; i < cnt; ++i) atomicAdd(&lcount[node_lvl[b*MAXN + i]], 1);
    percnt[b] = cnt;
  }
  __syncthreads();
  if (tid == 0){
    int off = 0;
    for (int lv = 1; lv <= MAXLVL; ++lv){
      loff[lv] = off;
      level_off[lv] = off;
      level_count[lv] = lcount[lv];
      off += lcount[lv];
    }
  }
  __syncthreads();
  if (tid < BB){
    int b = tid;
    int cnt = percnt[b];
    for (int i = 0; i < cnt; ++i){
      int gid = b*MAXN + i;
      int lv = node_lvl[gid];
      int p = atomicAdd(&lcur[lv], 1);
      order[loff[lv] + p] = gid;
    }
  }
}

// ---------------------------------------------------------------------------
// Level GEMM: gates_part[kq][slot][row] = sum_{k in kq chunk} V[slot][k]*Wc[row][k]
// V gathered on the fly from (hs | nodeH | zeros). Tiles: 64 nodes x 64 rows x K16.
// grid = (96 row-groups, 6 node-groups, 4 k-quarters)
__global__ __launch_bounds__(256) void k_level_gemm(const float* __restrict__ Wc,
    const float* __restrict__ hs, const float* __restrict__ nodeH,
    const int* __restrict__ node_l, const int* __restrict__ node_r,
    const int* __restrict__ node_x, const int* __restrict__ node_b,
    const int* __restrict__ level_count, const int* __restrict__ level_off,
    const int* __restrict__ order, float* __restrict__ gates_part, int lvl){
  int n = level_count[lvl];
  int ng = blockIdx.y;
  if (ng*64 >= n) return;
  int rg = blockIdx.x;
  int kq = blockIdx.z;
  __shared__ float as[16][68];      // V tile   [kk][node-slot]
  __shared__ float bs[16][68];      // Wc tile  [kk][row-local]
  __shared__ const float* srcp[64][3];
  int tid = threadIdx.x;
  if (tid < 64){
    int ns = tid;
    const float* p0 = nullptr; const float* p1 = nullptr; const float* p2 = nullptr;
    if (ng*64 + ns < n){
      int gid = order[level_off[lvl] + ng*64 + ns];
      int b = node_b[gid];
      int el = node_l[gid], er = node_r[gid], xt = node_x[gid];
      p0 = (el < 0) ? nullptr : (el >= 10000 ? &hs[(size_t)(b*LL + (el-10000))*HH]
                                             : &nodeH[(size_t)el*HH]);
      p1 = (er < 0) ? nullptr : (er >= 10000 ? &hs[(size_t)(b*LL + (er-10000))*HH]
                                             : &nodeH[(size_t)er*HH]);
      p2 = &hs[(size_t)(b*LL + xt)*HH];
    }
    srcp[ns][0] = p0; srcp[ns][1] = p1; srcp[ns][2] = p2;
  }
  __syncthreads();
  int nt = tid & 15, rt = tid >> 4;
  float acc[4][4] = {};
  for (int kc = 0; kc < 768; kc += 16){
    #pragma unroll
    for (int it = 0; it < 4; ++it){
      int idx = it*256 + tid;
      int kk = idx & 15, ss = idx >> 4;
      int kglob = kq*768 + kc + kk;
      int part = kglob >> 10, kloc = kglob & 1023;
      const float* p = srcp[ss][part];
      as[kk][ss] = p ? p[kloc] : 0.f;
      bs[kk][ss] = Wc[(size_t)(rg*64 + ss)*K3H + kglob];
    }
    __syncthreads();
    #pragma unroll
    for (int kk = 0; kk < 16; ++kk){
      float a4[4], b4[4];
      #pragma unroll
      for (int i = 0; i < 4; ++i) a4[i] = as[kk][nt*4+i];
      #pragma unroll
      for (int i = 0; i < 4; ++i) b4[i] = bs[kk][rt*4+i];
      #pragma unroll
      for (int i = 0; i < 4; ++i)
        #pragma unroll
        for (int j2 = 0; j2 < 4; ++j2) acc[i][j2] += a4[i]*b4[j2];
    }
    __syncthreads();
  }
  #pragma unroll
  for (int i = 0; i < 4; ++i){
    int slot = ng*64 + nt*4 + i;
    #pragma unroll
    for (int j2 = 0; j2 < 4; ++j2){
      int row = rg*64 + rt*4 + j2;
      gates_part[((size_t)kq*MAXNPL + slot)*NG6 + row] = acc[i][j2];
    }
  }
}

// ---------------------------------------------------------------------------
// Level epilogue: reduce 4 k-partials, add bias, apply nary tree-LSTM cell.
// grid = (4 j-chunks, 384 node-slots), block 256.
__global__ __launch_bounds__(256) void k_level_epi(const float* __restrict__ gates_part,
    const float* __restrict__ bc, const float* __restrict__ cs,
    float* __restrict__ nodeH, float* __restrict__ nodeC,
    const int* __restrict__ node_l, const int* __restrict__ node_r,
    const int* __restrict__ node_x, const int* __restrict__ node_b,
    const int* __restrict__ node_root, const int* __restrict__ level_count,
    const int* __restrict__ level_off, const int* __restrict__ order,
    float* __restrict__ out, int lvl){
  int n = level_count[lvl];
  int ns = blockIdx.y;
  if (ns >= n) return;
  int j = blockIdx.x*256 + threadIdx.x;
  int gid = order[level_off[lvl] + ns];
  int b = node_b[gid];
  int el = node_l[gid], er = node_r[gid], xt = node_x[gid];
  float g[6];
  #pragma unroll
  for (int gg = 0; gg < 6; ++gg){
    float s = bc[gg*HH + j];
    #pragma unroll
    for (int kq = 0; kq < 4; ++kq)
      s += gates_part[((size_t)kq*MAXNPL + ns)*NG6 + gg*HH + j];
    g[gg] = s;
  }
  float lc = (el < 0) ? 0.f : (el >= 10000 ? cs[(size_t)(b*LL + (el-10000))*HH + j]
                                           : nodeC[(size_t)el*HH + j]);
  float rc = (er < 0) ? 0.f : (er >= 10000 ? cs[(size_t)(b*LL + (er-10000))*HH + j]
                                           : nodeC[(size_t)er*HH + j]);
  float xc = cs[(size_t)(b*LL + xt)*HH + j];
  // gate order: i, f_left, f_right, f_x, u, o
  float c = sigf(g[0])*tanhf(g[4]) + sigf(g[1])*lc + sigf(g[2])*rc + sigf(g[3])*xc;
  float h = sigf(g[5])*tanhf(c);
  nodeH[(size_t)gid*HH + j] = h;
  nodeC[(size_t)gid*HH + j] = c;
  if (node_root[gid]){
    out[(size_t)b*HH + j] = h;
    out[(size_t)BB*HH + (size_t)b*HH + j] = c;
  }
}

// ---------------------------------------------------------------------------
extern "C" void kernel_launch(void* const* d_in, const int* in_sizes, int n_in,
                              void* d_out, int out_size, void* d_ws, size_t ws_size,
                              hipStream_t stream){
  const float* se  = (const float*)d_in[0];   // [16,48,1024]
  const float* gu  = (const float*)d_in[1];   // [16,48]
  const float* Wih = (const float*)d_in[2];   // [4096,1024]
  const float* Whh = (const float*)d_in[3];   // [4096,1024]
  const float* bih = (const float*)d_in[4];   // [4096]
  const float* bhh = (const float*)d_in[5];   // [4096]
  const float* R1  = (const float*)d_in[6];   // [128,1024]
  const float* R2  = (const float*)d_in[7];   // [1,128]
  const float* Wc  = (const float*)d_in[8];   // [6144,3072]
  const float* bc  = (const float*)d_in[9];   // [6144]
  const int*   len = (const int*)d_in[10];    // [16]
  float* out = (float*)d_out;                 // [2,16,1024] fp32

  float* ws = (float*)d_ws;
  size_t off = 0;
  float* Wt    = ws + off; off += (size_t)HH*NG4;        // Whh^T  [1024][4096]
  float* R1t   = ws + off; off += (size_t)HH*RANKH;      // R1^T   [1024][128]
  float* Gx    = ws + off; off += (size_t)BB*LL*NG4;     // input gates [768][4096]
  float* hs    = ws + off; off += (size_t)BB*LL*HH;
  float* cs    = ws + off; off += (size_t)BB*LL*HH;
  float* nodeH = ws + off; off += (size_t)TOTN*HH;
  float* nodeC = ws + off; off += (size_t)TOTN*HH;
  float* gpart = ws + off; off += (size_t)4*MAXNPL*NG6;  // k-split partial gates
  float* score = ws + off; off += 1024;
  float* snoi  = ws + off; off += 1024;
  int* ib = (int*)(ws + off);
  int* node_l    = ib; ib += 768;
  int* node_r    = ib; ib += 768;
  int* node_x    = ib; ib += 768;
  int* node_lvl  = ib; ib += 768;
  int* node_b    = ib; ib += 768;
  int* node_root = ib; ib += 768;
  int* level_count = ib; ib += 64;
  int* level_off   = ib; ib += 64;
  int* order       = ib; ib += 768;

  // 1. transposes
  k_transpose<<<dim3(32, 128), dim3(32, 8), 0, stream>>>(Whh, Wt, NG4, HH);
  k_transpose<<<dim3(32, 4),   dim3(32, 8), 0, stream>>>(R1, R1t, RANKH, HH);
  // 2. input-side gate GEMM (+ both biases)
  k_gemm_gx<<<dim3(12, 64), 256, 0, stream>>>(se, Wih, bih, bhh, Gx,
                                              BB*LL, NG4, HH);
  // 3. recurrent LSTM over 48 timesteps
  for (int t = 0; t < LL; ++t)
    k_lstm_step<<<128, 256, 0, stream>>>(Wt, Gx, hs, cs, t);
  // 4. per-position scores + gumbel noise
  k_score<<<BB*LL, 128, 0, stream>>>(R1t, R2, hs, gu, score, snoi);
  // 5. tree structure
  k_build<<<1, 64, 0, stream>>>(score, snoi, len, node_l, node_r, node_x,
                                node_lvl, node_b, node_root,
                                level_count, level_off, order);
  // 6. level-by-level nary compositions (worst-case 47 levels; empty levels exit)
  for (int lvl = 1; lvl <= MAXN; ++lvl){
    k_level_gemm<<<dim3(96, 6, 4), 256, 0, stream>>>(Wc, hs, nodeH,
        node_l, node_r, node_x, node_b, level_count, level_off, order,
        gpart, lvl);
    k_level_epi<<<dim3(4, MAXNPL), 256, 0, stream>>>(gpart, bc, cs,
        nodeH, nodeC, node_l, node_r, node_x, node_b, node_root,
        level_count, level_off, order, out, lvl);
  }
}

// Round 2
// 2649.787 us; speedup vs baseline: 1.4080x; 1.4080x over previous
//
#include <hip/hip_runtime.h>
#include <math.h>

#define BB 16
#define LL 48
#define HH 1024
#define NG4 4096      // 4*H
#define NG6 6144      // 6*H
#define K3H 3072      // 3*H
#define RANKH 128
#define MAXN 47       // max nodes per batch (len-1 <= 47)
#define TOTN (BB*MAXN)
#define MAXLVL 48
#define MAXNPL 384    // max nodes in one level

typedef __attribute__((ext_vector_type(8))) short bf16x8;
typedef __attribute__((ext_vector_type(4))) float f32x4;

__device__ __forceinline__ float sigf(float x){ return 1.f/(1.f + expf(-x)); }

__device__ __forceinline__ unsigned short f2bf(float f){
  union { float f; unsigned u; } v; v.f = f;
  unsigned r = v.u + 0x7fff + ((v.u >> 16) & 1);
  return (unsigned short)(r >> 16);
}

// ---------------------------------------------------------------------------
// fp32 -> bf16 (RNE), vectorized. n multiple of 1024.
__global__ __launch_bounds__(256) void k_cvt_bf16(const float* __restrict__ in,
    unsigned short* __restrict__ out, int n){
  int i = (blockIdx.x*256 + threadIdx.x)*4;
  if (i >= n) return;
  float4 v = *(const float4*)(in + i);
  ushort4 o;
  o.x = f2bf(v.x); o.y = f2bf(v.y); o.z = f2bf(v.z); o.w = f2bf(v.w);
  *(ushort4*)(out + i) = o;
}

// ---------------------------------------------------------------------------
// Generic 32x32 LDS-tiled transpose: out[C][R] = in[R][C]^T
__global__ __launch_bounds__(256) void k_transpose(const float* __restrict__ in,
                                                   float* __restrict__ out, int R, int C){
  __shared__ float t[32][33];
  int bx = blockIdx.x*32, by = blockIdx.y*32;
  int x = threadIdx.x, y = threadIdx.y;   // block (32,8)
  #pragma unroll
  for (int i = 0; i < 32; i += 8){
    int r = by + y + i, c = bx + x;
    if (r < R && c < C) t[y+i][x] = in[(size_t)r*C + c];
  }
  __syncthreads();
  #pragma unroll
  for (int i = 0; i < 32; i += 8){
    int r = bx + y + i, c = by + x;       // out dims [C][R]
    if (r < C && c < R) out[(size_t)r*R + c] = t[x][y+i];
  }
}

// ---------------------------------------------------------------------------
// Gx[m][n] = sum_k se[m][k]*Wih[n][k] + bih[n] + bhh[n]   (fp32 — decision path)
__global__ __launch_bounds__(256) void k_gemm_gx(const float* __restrict__ A,
    const float* __restrict__ Bw, const float* __restrict__ bih,
    const float* __restrict__ bhh, float* __restrict__ Cout, int M, int N, int K){
  __shared__ float as[16][68];
  __shared__ float bs[16][68];
  int m0 = blockIdx.x*64, n0 = blockIdx.y*64;
  int tid = threadIdx.x;
  int mt = tid & 15, nt = tid >> 4;
  float acc[4][4] = {};
  for (int k0 = 0; k0 < K; k0 += 16){
    #pragma unroll
    for (int it = 0; it < 4; ++it){
      int idx = it*256 + tid;
      int kk = idx & 15, mm = idx >> 4;
      as[kk][mm] = A[(size_t)(m0+mm)*K + k0 + kk];
      bs[kk][mm] = Bw[(size_t)(n0+mm)*K + k0 + kk];
    }
    __syncthreads();
    #pragma unroll
    for (int kk = 0; kk < 16; ++kk){
      float a4[4], b4[4];
      #pragma unroll
      for (int i = 0; i < 4; ++i) a4[i] = as[kk][mt*4+i];
      #pragma unroll
      for (int i = 0; i < 4; ++i) b4[i] = bs[kk][nt*4+i];
      #pragma unroll
      for (int i = 0; i < 4; ++i)
        #pragma unroll
        for (int j2 = 0; j2 < 4; ++j2) acc[i][j2] += a4[i]*b4[j2];
    }
    __syncthreads();
  }
  #pragma unroll
  for (int i = 0; i < 4; ++i){
    int m = m0 + mt*4 + i;
    #pragma unroll
    for (int j2 = 0; j2 < 4; ++j2){
      int n = n0 + nt*4 + j2;
      Cout[(size_t)m*N + n] = acc[i][j2] + bih[n] + bhh[n];
    }
  }
}

// ---------------------------------------------------------------------------
// One LSTM time step (fp32 — decision path). grid=128, block=256.
__global__ __launch_bounds__(256) void k_lstm_step(const float* __restrict__ Wt,
    const float* __restrict__ Gx, float* __restrict__ hs, float* __restrict__ cs, int t){
  __shared__ float hsm[2][HH];
  __shared__ float red[2][2][4][64];
  int tid = threadIdx.x;
  int bp = blockIdx.x >> 4, jc = blockIdx.x & 15;
  int w = tid >> 6, l = tid & 63;
  int bl = w >> 1;
  int kh = w & 1;
  int b0 = bp*2;
  if (t == 0){
    for (int i = tid; i < 2*HH; i += 256) ((float*)hsm)[i] = 0.f;
  } else {
    for (int i = tid; i < 2*HH; i += 256){
      int bb = i >> 10, k = i & 1023;
      ((float*)hsm)[i] = hs[(size_t)((b0+bb)*LL + (t-1))*HH + k];
    }
  }
  __syncthreads();
  int j = jc*64 + l;
  float acc0=0.f, acc1=0.f, acc2=0.f, acc3=0.f;
  const float* hrow = hsm[bl];
  for (int k = kh*512; k < kh*512 + 512; ++k){
    float hk = hrow[k];
    const float* wr = &Wt[(size_t)k*NG4 + j];
    acc0 += wr[0]    * hk;
    acc1 += wr[1024] * hk;
    acc2 += wr[2048] * hk;
    acc3 += wr[3072] * hk;
  }
  red[bl][kh][0][l] = acc0; red[bl][kh][1][l] = acc1;
  red[bl][kh][2][l] = acc2; red[bl][kh][3][l] = acc3;
  __syncthreads();
  if (tid < 128){
    int bb = tid >> 6, jl = tid & 63;
    int b = b0 + bb;
    int jj = jc*64 + jl;
    size_t grow = (size_t)(b*LL + t)*NG4;
    float gi = Gx[grow + 0*HH + jj] + red[bb][0][0][jl] + red[bb][1][0][jl];
    float gf = Gx[grow + 1*HH + jj] + red[bb][0][1][jl] + red[bb][1][1][jl];
    float gu = Gx[grow + 2*HH + jj] + red[bb][0][2][jl] + red[bb][1][2][jl];
    float go = Gx[grow + 3*HH + jj] + red[bb][0][3][jl] + red[bb][1][3][jl];
    float cp = (t == 0) ? 0.f : cs[(size_t)(b*LL + (t-1))*HH + jj];
    float c = sigf(gf)*cp + sigf(gi)*tanhf(gu);
    float h = sigf(go)*tanhf(c);
    cs[(size_t)(b*LL + t)*HH + jj] = c;
    hs[(size_t)(b*LL + t)*HH + jj] = h;
  }
}

// ---------------------------------------------------------------------------
// Per-position rank-MLP score + gumbel noise (fp32 — decision path).
__global__ __launch_bounds__(128) void k_score(const float* __restrict__ R1t,
    const float* __restrict__ R2, const float* __restrict__ hs,
    const float* __restrict__ gumbel_u, float* __restrict__ score,
    float* __restrict__ snoisy){
  __shared__ float hsm[HH];
  __shared__ float red[128];
  int bt = blockIdx.x;
  int tid = threadIdx.x;
  for (int i = tid; i < HH; i += 128) hsm[i] = hs[(size_t)bt*HH + i];
  __syncthreads();
  float acc = 0.f;
  for (int k = 0; k < HH; ++k) acc += R1t[(size_t)k*RANKH + tid] * hsm[k];
  red[tid] = fmaxf(acc, 0.f) * R2[tid];
  __syncthreads();
  for (int s = 64; s > 0; s >>= 1){
    if (tid < s) red[tid] += red[tid+s];
    __syncthreads();
  }
  if (tid == 0){
    float s = red[0];
    float u = gumbel_u[bt];
    float noise = -logf(-logf(u));
    score[bt]  = s;
    snoisy[bt] = s + noise;
  }
}

// ---------------------------------------------------------------------------
// Build the tree structure for all batches. 1 block, 64 threads.
__global__ __launch_bounds__(64) void k_build(const float* __restrict__ score,
    const float* __restrict__ snoisy, const int* __restrict__ length,
    int* __restrict__ node_l, int* __restrict__ node_r, int* __restrict__ node_x,
    int* __restrict__ node_lvl, int* __restrict__ node_b, int* __restrict__ node_root,
    int* __restrict__ level_count, int* __restrict__ level_off, int* __restrict__ order){
  __shared__ float sc[BB*LL], sn[BB*LL];
  __shared__ int lcount[MAXLVL+1], lcur[MAXLVL+1], loff[MAXLVL+1];
  __shared__ int percnt[BB];
  int tid = threadIdx.x;
  for (int i = tid; i < BB*LL; i += 64){ sc[i] = score[i]; sn[i] = snoisy[i]; }
  for (int i = tid; i <= MAXLVL; i += 64){ lcount[i] = 0; lcur[i] = 0; }
  __syncthreads();
  if (tid < BB){
    int b = tid;
    int len = length[b];
    if (len > LL) len = LL;
    int qs[MAXN], qe[MAXN], qn[MAXN];
    int qh = 0, qt = 0, cnt = 0;
    int rootn = cnt++;
    qs[qt] = 0; qe[qt] = len; qn[qt] = rootn; qt++;
    while (qh < qt){
      int s0 = qs[qh], e0 = qe[qh], nid = qn[qh]; qh++;
      float best = sc[b*LL + s0]; int pos = s0;
      for (int t2 = s0+1; t2 < e0; ++t2){
        float v = sc[b*LL + t2];
        if (v > best){ best = v; pos = t2; }
      }
      float bestn = sn[b*LL + s0]; int js = s0;
      for (int t2 = s0+1; t2 < e0; ++t2){
        float v = sn[b*LL + t2];
        if (v > bestn){ bestn = v; js = t2; }
      }
      int gid = b*MAXN + nid;
      node_x[gid] = js;
      node_b[gid] = b;
      node_root[gid] = (nid == 0) ? 1 : 0;
      int ln = pos - s0, enc_l, enc_r;
      if (ln <= 0) enc_l = -1;
      else if (ln == 1) enc_l = 10000 + s0;
      else { int c2 = cnt++; enc_l = b*MAXN + c2; qs[qt]=s0; qe[qt]=pos; qn[qt]=c2; qt++; }
      int rn = e0 - (pos+1);
      if (rn <= 0) enc_r = -1;
      else if (rn == 1) enc_r = 10000 + (pos+1);
      else { int c2 = cnt++; enc_r = b*MAXN + c2; qs[qt]=pos+1; qe[qt]=e0; qn[qt]=c2; qt++; }
      node_l[gid] = enc_l; node_r[gid] = enc_r;
    }
    for (int i = cnt-1; i >= 0; --i){
      int gid = b*MAXN + i;
      int el = node_l[gid], er = node_r[gid];
      int llv = (el >= 0 && el < 10000) ? node_lvl[el] : 0;
      int rlv = (er >= 0 && er < 10000) ? node_lvl[er] : 0;
      node_lvl[gid] = 1 + (llv > rlv ? llv : rlv);
    }
    for (int i = 0; i < cnt; ++i) atomicAdd(&lcount[node_lvl[b*MAXN + i]], 1);
    percnt[b] = cnt;
  }
  __syncthreads();
  if (tid == 0){
    int off = 0;
    for (int lv = 1; lv <= MAXLVL; ++lv){
      loff[lv] = off;
      level_off[lv] = off;
      level_count[lv] = lcount[lv];
      off += lcount[lv];
    }
  }
  __syncthreads();
  if (tid < BB){
    int b = tid;
    int cnt = percnt[b];
    for (int i = 0; i < cnt; ++i){
      int gid = b*MAXN + i;
      int lv = node_lvl[gid];
      int p = atomicAdd(&lcur[lv], 1);
      order[loff[lv] + p] = gid;
    }
  }
}

// ---------------------------------------------------------------------------
// Level GEMM, bf16 MFMA: gates[slot][row] = sum_k V[slot][k]*Wc[row][k]
// V gathered bf16 from (hs_bf | nodeH_bf | zeros). Block: 64 nodes x 64 rows,
// full K=3072. 4 waves in 2x2, each wave 2x2 MFMA 16x16x32 tiles.
// grid = (96 row-groups, ceil-active node-groups<=6)
__global__ __launch_bounds__(256) void k_level_mfma(
    const unsigned short* __restrict__ Wc_bf,
    const unsigned short* __restrict__ hs_bf,
    const unsigned short* __restrict__ nodeH_bf,
    const int* __restrict__ node_l, const int* __restrict__ node_r,
    const int* __restrict__ node_x, const int* __restrict__ node_b,
    const int* __restrict__ level_count, const int* __restrict__ level_off,
    const int* __restrict__ order, float* __restrict__ gates, int lvl){
  int n = level_count[lvl];
  int ng = blockIdx.y;
  if (ng*64 >= n) return;
  int rg = blockIdx.x;
  __shared__ unsigned short As[64][40];   // 80B row stride: 16B-aligned, 2-way banks (free)
  __shared__ unsigned short Bs[64][40];
  __shared__ const unsigned short* srcp[64][3];
  int tid = threadIdx.x;
  if (tid < 64){
    const unsigned short *p0 = nullptr, *p1 = nullptr, *p2 = nullptr;
    if (ng*64 + tid < n){
      int gid = order[level_off[lvl] + ng*64 + tid];
      int b = node_b[gid];
      int el = node_l[gid], er = node_r[gid], xt = node_x[gid];
      p0 = (el < 0) ? nullptr : (el >= 10000 ? hs_bf + (size_t)(b*LL + (el-10000))*HH
                                             : nodeH_bf + (size_t)el*HH);
      p1 = (er < 0) ? nullptr : (er >= 10000 ? hs_bf + (size_t)(b*LL + (er-10000))*HH
                                             : nodeH_bf + (size_t)er*HH);
      p2 = hs_bf + (size_t)(b*LL + xt)*HH;
    }
    srcp[tid][0] = p0; srcp[tid][1] = p1; srcp[tid][2] = p2;
  }
  __syncthreads();
  int wave = tid >> 6, lane = tid & 63;
  int wm = wave >> 1, wn = wave & 1;
  f32x4 acc[2][2] = {{{0.f,0.f,0.f,0.f},{0.f,0.f,0.f,0.f}},
                     {{0.f,0.f,0.f,0.f},{0.f,0.f,0.f,0.f}}};
  int arow = tid >> 2;            // staging row 0..63
  int koff = (tid & 3) * 8;       // elems within K32 chunk
  const unsigned short* Brow = Wc_bf + (size_t)(rg*64 + arow)*K3H + koff;
  int fr = lane & 15, fk = (lane >> 4) * 8;
  for (int k0 = 0; k0 < K3H; k0 += 32){
    int part = k0 >> 10, kloc = k0 & 1023;
    const unsigned short* p = srcp[arow][part];
    uint4 av = p ? *(const uint4*)(p + kloc + koff) : make_uint4(0u,0u,0u,0u);
    uint4 bv = *(const uint4*)(Brow + k0);
    __syncthreads();                 // previous iter's frag reads done
    *(uint4*)&As[arow][koff] = av;
    *(uint4*)&Bs[arow][koff] = bv;
    __syncthreads();
    bf16x8 a0 = *(bf16x8*)&As[wm*32 +      fr][fk];
    bf16x8 a1 = *(bf16x8*)&As[wm*32 + 16 + fr][fk];
    bf16x8 b0 = *(bf16x8*)&Bs[wn*32 +      fr][fk];
    bf16x8 b1 = *(bf16x8*)&Bs[wn*32 + 16 + fr][fk];
    acc[0][0] = __builtin_amdgcn_mfma_f32_16x16x32_bf16(a0, b0, acc[0][0], 0, 0, 0);
    acc[0][1] = __builtin_amdgcn_mfma_f32_16x16x32_bf16(a0, b1, acc[0][1], 0, 0, 0);
    acc[1][0] = __builtin_amdgcn_mfma_f32_16x16x32_bf16(a1, b0, acc[1][0], 0, 0, 0);
    acc[1][1] = __builtin_amdgcn_mfma_f32_16x16x32_bf16(a1, b1, acc[1][1], 0, 0, 0);
  }
  int crow4 = (lane >> 4)*4, ccol = lane & 15;
  #pragma unroll
  for (int ti = 0; ti < 2; ++ti)
    #pragma unroll
    for (int tj = 0; tj < 2; ++tj)
      #pragma unroll
      for (int r = 0; r < 4; ++r){
        int m = wm*32 + ti*16 + crow4 + r;      // node slot (local)
        int nn = wn*32 + tj*16 + ccol;          // Wc row (local)
        gates[(size_t)(ng*64 + m)*NG6 + rg*64 + nn] = acc[ti][tj][r];
      }
}

// ---------------------------------------------------------------------------
// Level epilogue: add bias, apply nary tree-LSTM cell; h stored as bf16.
// grid = (4 j-chunks, MAXNPL node-slots), block 256.
__global__ __launch_bounds__(256) void k_level_epi(const float* __restrict__ gates,
    const float* __restrict__ bc, const float* __restrict__ cs,
    unsigned short* __restrict__ nodeH_bf, float* __restrict__ nodeC,
    const int* __restrict__ node_l, const int* __restrict__ node_r,
    const int* __restrict__ node_x, const int* __restrict__ node_b,
    const int* __restrict__ node_root, const int* __restrict__ level_count,
    const int* __restrict__ level_off, const int* __restrict__ order,
    float* __restrict__ out, int lvl){
  int n = level_count[lvl];
  int ns = blockIdx.y;
  if (ns >= n) return;
  int j = blockIdx.x*256 + threadIdx.x;
  int gid = order[level_off[lvl] + ns];
  int b = node_b[gid];
  int el = node_l[gid], er = node_r[gid], xt = node_x[gid];
  float g[6];
  #pragma unroll
  for (int gg = 0; gg < 6; ++gg)
    g[gg] = bc[gg*HH + j] + gates[(size_t)ns*NG6 + gg*HH + j];
  float lc = (el < 0) ? 0.f : (el >= 10000 ? cs[(size_t)(b*LL + (el-10000))*HH + j]
                                           : nodeC[(size_t)el*HH + j]);
  float rc = (er < 0) ? 0.f : (er >= 10000 ? cs[(size_t)(b*LL + (er-10000))*HH + j]
                                           : nodeC[(size_t)er*HH + j]);
  float xc = cs[(size_t)(b*LL + xt)*HH + j];
  float c = sigf(g[0])*tanhf(g[4]) + sigf(g[1])*lc + sigf(g[2])*rc + sigf(g[3])*xc;
  float h = sigf(g[5])*tanhf(c);
  nodeH_bf[(size_t)gid*HH + j] = f2bf(h);
  nodeC[(size_t)gid*HH + j] = c;
  if (node_root[gid]){
    out[(size_t)b*HH + j] = h;
    out[(size_t)BB*HH + (size_t)b*HH + j] = c;
  }
}

// ---------------------------------------------------------------------------
extern "C" void kernel_launch(void* const* d_in, const int* in_sizes, int n_in,
                              void* d_out, int out_size, void* d_ws, size_t ws_size,
                              hipStream_t stream){
  const float* se  = (const float*)d_in[0];
  const float* gu  = (const float*)d_in[1];
  const float* Wih = (const float*)d_in[2];
  const float* Whh = (const float*)d_in[3];
  const float* bih = (const float*)d_in[4];
  const float* bhh = (const float*)d_in[5];
  const float* R1  = (const float*)d_in[6];
  const float* R2  = (const float*)d_in[7];
  const float* Wc  = (const float*)d_in[8];
  const float* bc  = (const float*)d_in[9];
  const int*   len = (const int*)d_in[10];
  float* out = (float*)d_out;                 // [2,16,1024] fp32

  float* ws = (float*)d_ws;
  size_t off = 0;
  float* Wt    = ws + off; off += (size_t)HH*NG4;        // Whh^T fp32
  float* R1t   = ws + off; off += (size_t)HH*RANKH;      // R1^T fp32
  float* Gx    = ws + off; off += (size_t)BB*LL*NG4;     // input gates fp32
  float* hs    = ws + off; off += (size_t)BB*LL*HH;      // fp32 (decision path)
  float* cs    = ws + off; off += (size_t)BB*LL*HH;      // fp32
  float* nodeC = ws + off; off += (size_t)TOTN*HH;       // fp32
  float* gates = ws + off; off += (size_t)MAXNPL*NG6;    // fp32 level gates
  unsigned short* Wc_bf    = (unsigned short*)(ws + off); off += (size_t)NG6*K3H/2;
  unsigned short* hs_bf    = (unsigned short*)(ws + off); off += (size_t)BB*LL*HH/2;
  unsigned short* nodeH_bf = (unsigned short*)(ws + off); off += (size_t)TOTN*HH/2 + 512;
  float* score = ws + off; off += 1024;
  float* snoi  = ws + off; off += 1024;
  int* ib = (int*)(ws + off);
  int* node_l    = ib; ib += 768;
  int* node_r    = ib; ib += 768;
  int* node_x    = ib; ib += 768;
  int* node_lvl  = ib; ib += 768;
  int* node_b    = ib; ib += 768;
  int* node_root = ib; ib += 768;
  int* level_count = ib; ib += 64;
  int* level_off   = ib; ib += 64;
  int* order       = ib; ib += 768;

  // 1. transposes + Wc bf16 conversion
  k_transpose<<<dim3(32, 128), dim3(32, 8), 0, stream>>>(Whh, Wt, NG4, HH);
  k_transpose<<<dim3(32, 4),   dim3(32, 8), 0, stream>>>(R1, R1t, RANKH, HH);
  k_cvt_bf16<<<(NG6*K3H)/1024, 256, 0, stream>>>(Wc, Wc_bf, NG6*K3H);
  // 2. input-side gate GEMM (+ both biases)
  k_gemm_gx<<<dim3(12, 64), 256, 0, stream>>>(se, Wih, bih, bhh, Gx, BB*LL, NG4, HH);
  // 3. recurrent LSTM over 48 timesteps (fp32)
  for (int t = 0; t < LL; ++t)
    k_lstm_step<<<128, 256, 0, stream>>>(Wt, Gx, hs, cs, t);
  // 3b. hs -> bf16 for the composition GEMMs
  k_cvt_bf16<<<(BB*LL*HH)/1024, 256, 0, stream>>>(hs, hs_bf, BB*LL*HH);
  // 4. per-position scores + gumbel noise (fp32)
  k_score<<<BB*LL, 128, 0, stream>>>(R1t, R2, hs, gu, score, snoi);
  // 5. tree structure
  k_build<<<1, 64, 0, stream>>>(score, snoi, len, node_l, node_r, node_x,
                                node_lvl, node_b, node_root,
                                level_count, level_off, order);
  // 6. level-by-level nary compositions (bf16 MFMA GEMM + fp32 cell epilogue)
  for (int lvl = 1; lvl <= MAXN; ++lvl){
    k_level_mfma<<<dim3(96, 6), 256, 0, stream>>>(Wc_bf, hs_bf, nodeH_bf,
        node_l, node_r, node_x, node_b, level_count, level_off, order,
        gates, lvl);
    k_level_epi<<<dim3(4, MAXNPL), 256, 0, stream>>>(gates, bc, cs,
        nodeH_bf, nodeC, node_l, node_r, node_x, node_b, node_root,
        level_count, level_off, order, out, lvl);
  }
}